// Round 4
// baseline (435.114 us; speedup 1.0000x reference)
//
#include <hip/hip_runtime.h>

// Problem constants (fixed by the reference: shape (20,1,128,128,128) fp32)
#define NBATCH 20
#define ELEMS_PER_BATCH (128 * 128 * 128)       // 2,097,152
#define BATCH_F4 (ELEMS_PER_BATCH / 4)          // 524,288 float4 per batch
#define THREADS 256
#define GRID_BLOCKS 2048                        // 2048*256 threads == BATCH_F4 exactly:
                                                // grid-stride step s covers exactly batch s.
                                                // 2048 blocks = 8/CU = 32 waves/CU, no tail.

#define LN2 0.69314718055994530942
// torch clamps log at -100 -> in log2 space: -100/ln2
#define LOG2_CLAMP (-144.26950408889634f)

// Native clang vector type (__builtin_nontemporal_load rejects HIP_vector_type).
typedef float f4 __attribute__((ext_vector_type(4)));

// Round-4: R3's nt loads (proven +33us: mixed L3/HBM service path was capping
// at 2.84 TB/s; nt -> ~3.95 TB/s) + max occupancy. R1 measured 43% occupancy
// at 20 waves/CU; harness fill kernels prove ~6.9 TB/s streams are possible.
// This shape: exactly-resident flat grid, 32 waves/CU, depth-2 ping-pong.
// Per-batch POR counts: wave shfl_xor reduce of packed (pc | tc<<16), one LDS
// atomic per wave per batch (4 waves * 20 batches = 80 LDS atomics/block).

__global__ __launch_bounds__(THREADS, 8) void partial_kernel(
    const float* __restrict__ x, const float* __restrict__ y,
    float* __restrict__ bce_part, int* __restrict__ comb_part) {
  const int tid = threadIdx.x;
  const int gid = blockIdx.x * THREADS + tid;   // 0 .. BATCH_F4-1

  const f4* __restrict__ x4 = (const f4*)x;
  const f4* __restrict__ y4 = (const f4*)y;

  __shared__ int sc[NBATCH];                    // packed per-block per-batch counts
  if (tid < NBATCH) sc[tid] = 0;
  __syncthreads();

  float bce2 = 0.0f;                            // BCE sum in log2 units (global, no batch split)

  f4 xa, ya, xb, yb;
  xa = __builtin_nontemporal_load(&x4[gid]);
  ya = __builtin_nontemporal_load(&y4[gid]);

  // Process one float4 pair for batch S: BCE accumulate + wave-reduced counts.
#define PROCESS(XV, YV, S)                                                     \
  {                                                                            \
    int pc = 0, tc = 0;                                                        \
    _Pragma("unroll")                                                          \
    for (int c = 0; c < 4; ++c) {                                              \
      const float xx = XV[c];                                                  \
      const float yy = YV[c];                                                  \
      const float lx = fmaxf(__builtin_amdgcn_logf(xx),        LOG2_CLAMP);    \
      const float l1 = fmaxf(__builtin_amdgcn_logf(1.0f - xx), LOG2_CLAMP);    \
      bce2 += l1 + yy * (lx - l1); /* y*lx+(1-y)*l1 */                         \
      pc += (xx <= 0.5f);                                                      \
      tc += (yy < 1.0f);                                                       \
    }                                                                          \
    int packed = pc | (tc << 16); /* per-wave sums <= 256 per field: no carry */\
    _Pragma("unroll")                                                          \
    for (int o = 32; o > 0; o >>= 1) packed += __shfl_xor(packed, o);          \
    if ((tid & 63) == 0) atomicAdd(&sc[S], packed);                            \
  }

  // Depth-2 ping-pong: issue batch S+1 loads before computing batch S.
#define STEP(CX, CY, NX, NY, S)                                                \
  if ((S) + 1 < NBATCH) {                                                      \
    NX = __builtin_nontemporal_load(&x4[((S) + 1) * BATCH_F4 + gid]);          \
    NY = __builtin_nontemporal_load(&y4[((S) + 1) * BATCH_F4 + gid]);          \
  }                                                                            \
  PROCESS(CX, CY, S)

  STEP(xa, ya, xb, yb, 0)   STEP(xb, yb, xa, ya, 1)
  STEP(xa, ya, xb, yb, 2)   STEP(xb, yb, xa, ya, 3)
  STEP(xa, ya, xb, yb, 4)   STEP(xb, yb, xa, ya, 5)
  STEP(xa, ya, xb, yb, 6)   STEP(xb, yb, xa, ya, 7)
  STEP(xa, ya, xb, yb, 8)   STEP(xb, yb, xa, ya, 9)
  STEP(xa, ya, xb, yb, 10)  STEP(xb, yb, xa, ya, 11)
  STEP(xa, ya, xb, yb, 12)  STEP(xb, yb, xa, ya, 13)
  STEP(xa, ya, xb, yb, 14)  STEP(xb, yb, xa, ya, 15)
  STEP(xa, ya, xb, yb, 16)  STEP(xb, yb, xa, ya, 17)
  STEP(xa, ya, xb, yb, 18)  STEP(xb, yb, xa, ya, 19)
#undef STEP
#undef PROCESS

  // Block-reduce BCE.
  __shared__ float sb[THREADS];
  sb[tid] = bce2;
  __syncthreads();                              // also fences the sc[] atomics
#pragma unroll
  for (int s = THREADS / 2; s > 0; s >>= 1) {
    if (tid < s) sb[tid] += sb[tid + s];
    __syncthreads();
  }
  if (tid == 0) bce_part[blockIdx.x] = sb[0] * (float)LN2;  // back to ln units
  if (tid < NBATCH) comb_part[tid * GRID_BLOCKS + blockIdx.x] = sc[tid];
}

// Kernel 2: single block. Double-precision BCE total; per-batch POR; compose.
__global__ __launch_bounds__(THREADS) void final_kernel(
    const float* __restrict__ bce_part, const int* __restrict__ comb_part,
    float* __restrict__ out) {
  const int tid = threadIdx.x;

  __shared__ double sred[THREADS];
  double local = 0.0;
  for (int i = tid; i < GRID_BLOCKS; i += THREADS) local += (double)bce_part[i];
  sred[tid] = local;
  __syncthreads();
#pragma unroll
  for (int s = THREADS / 2; s > 0; s >>= 1) {
    if (tid < s) sred[tid] += sred[tid + s];
    __syncthreads();
  }

  __shared__ int pcb[NBATCH], tcb[NBATCH];
  if (tid < NBATCH) { pcb[tid] = 0; tcb[tid] = 0; }
  __syncthreads();
  for (int s = 0; s < NBATCH; ++s) {
    int pl = 0, tl = 0;
    for (int i = tid; i < GRID_BLOCKS; i += THREADS) {
      const int c = comb_part[s * GRID_BLOCKS + i];
      pl += c & 0xFFFF;
      tl += (c >> 16) & 0xFFFF;
    }
    // 64-bit pack for the wave reduce: per-batch totals reach 2^21 > 16 bits.
    long long packed = (long long)pl | ((long long)tl << 32);
#pragma unroll
    for (int o = 32; o > 0; o >>= 1) packed += __shfl_xor(packed, o);
    if ((tid & 63) == 0) {
      atomicAdd(&pcb[s], (int)(packed & 0xFFFFFFFFll));
      atomicAdd(&tcb[s], (int)(packed >> 32));
    }
  }
  __syncthreads();

  __shared__ float spor[NBATCH];
  if (tid < NBATCH) {
    const float pp = (float)pcb[tid] / (float)ELEMS_PER_BATCH;
    const float pt = (float)tcb[tid] / (float)ELEMS_PER_BATCH;
    const float d = pp - pt;
    spor[tid] = d * d;
  }
  __syncthreads();

  if (tid == 0) {
    float pore_sum = 0.0f;
#pragma unroll
    for (int b = 0; b < NBATCH; ++b) pore_sum += spor[b];
    const float pore = pore_sum / (float)NBATCH;
    const double total = (double)NBATCH * (double)ELEMS_PER_BATCH;
    const float mse = (float)(-(sred[0] / total));
    out[0] = pore + mse;
    out[1] = pore;
  }
}

extern "C" void kernel_launch(void* const* d_in, const int* in_sizes, int n_in,
                              void* d_out, int out_size, void* d_ws, size_t ws_size,
                              hipStream_t stream) {
  const float* x = (const float*)d_in[0];
  const float* y = (const float*)d_in[1];
  float* out = (float*)d_out;

  // Workspace: [GRID_BLOCKS floats bce][NBATCH*GRID_BLOCKS ints packed counts].
  // Every slot is fully overwritten by partial_kernel — no init needed.
  float* bce_part  = (float*)d_ws;
  int*   comb_part = (int*)(bce_part + GRID_BLOCKS);

  partial_kernel<<<GRID_BLOCKS, THREADS, 0, stream>>>(x, y, bce_part, comb_part);
  final_kernel<<<1, THREADS, 0, stream>>>(bce_part, comb_part, out);
}

// Round 6
// 311.073 us; speedup vs baseline: 1.3988x; 1.3988x over previous
//
#include <hip/hip_runtime.h>

// Problem constants (fixed by the reference: shape (20,1,128,128,128) fp32)
#define NBATCH 20
#define ELEMS_PER_BATCH (128 * 128 * 128)       // 2,097,152 = 2^21
#define BATCH_F4 (ELEMS_PER_BATCH / 4)          // 524,288 = 2^19 float4 per batch
#define TOTAL_F4 (NBATCH * BATCH_F4)            // 10,485,760
#define THREADS 256
#define GRID_BLOCKS 2048                        // 8 blocks/CU = 32 waves/CU, single round, no tail
#define BLK_F4 (TOTAL_F4 / GRID_BLOCKS)         // 5120 contiguous f4 per block
#define NSTEP (BLK_F4 / THREADS)                // 20 f4 per thread

#define LN2 0.69314718055994530942
// torch clamps log at -100 -> in log2 space: -100/ln2
#define LOG2_CLAMP (-144.26950408889634f)

// Native clang vector type (__builtin_nontemporal_load rejects HIP_vector_type).
typedef float f4 __attribute__((ext_vector_type(4)));

// Round-5 (resubmit; R5 bench was an infra failure, kernel never ran).
// Keep R3's proven wins: nt loads (2.84->3.95 TB/s) + depth-2 ping-pong.
// Fix R4's failure: __launch_bounds__(256,8) capped VGPR at 32 ->
// ping-pong buffers spilled to scratch (WRITE_SIZE 247 MB/dispatch!) ->
// 435 us. Here: flat 2048-block CONTIGUOUS partition (exactly resident,
// 32 waves/CU, zero tail) with NO min-wave forcing. Batch boundaries are
// handled with two count accumulators per thread (batch id = f4_idx>>19,
// one shift; only 19/2048 blocks straddle a boundary).
__global__ __launch_bounds__(THREADS) void partial_kernel(
    const float* __restrict__ x, const float* __restrict__ y,
    float* __restrict__ bce_part, int* __restrict__ comb_part) {
  const int tid = threadIdx.x;
  const int blk = blockIdx.x;
  const long base = (long)blk * BLK_F4 + tid;
  const int s0 = (int)((unsigned)(blk * BLK_F4) >> 19);  // first batch in block

  const f4* __restrict__ x4 = (const f4*)x;
  const f4* __restrict__ y4 = (const f4*)y;

  float bce2 = 0.0f;                 // BCE sum in log2 units
  int pcA = 0, tcA = 0;              // counts for batch s0
  int pcB = 0, tcB = 0;              // counts for batch s0+1 (straddling blocks only)

  f4 xa, ya, xb, yb;
  xa = __builtin_nontemporal_load(&x4[base]);
  ya = __builtin_nontemporal_load(&y4[base]);

#define STEP(CX, CY, NX, NY, K)                                                \
  if ((K) + 1 < NSTEP) {                                                       \
    NX = __builtin_nontemporal_load(&x4[base + ((K) + 1) * THREADS]);          \
    NY = __builtin_nontemporal_load(&y4[base + ((K) + 1) * THREADS]);          \
  }                                                                            \
  {                                                                            \
    const int s = (int)((unsigned)(blk * BLK_F4 + (K) * THREADS + tid) >> 19); \
    int pc = 0, tc = 0;                                                        \
    _Pragma("unroll")                                                          \
    for (int c = 0; c < 4; ++c) {                                              \
      const float xx = CX[c];                                                  \
      const float yy = CY[c];                                                  \
      const float lx = fmaxf(__builtin_amdgcn_logf(xx),        LOG2_CLAMP);    \
      const float l1 = fmaxf(__builtin_amdgcn_logf(1.0f - xx), LOG2_CLAMP);    \
      bce2 += l1 + yy * (lx - l1); /* y*lx + (1-y)*l1 */                       \
      pc += (xx <= 0.5f);                                                      \
      tc += (yy < 1.0f);                                                       \
    }                                                                          \
    if (s == s0) { pcA += pc; tcA += tc; }                                     \
    else         { pcB += pc; tcB += tc; }                                     \
  }

  STEP(xa, ya, xb, yb, 0)   STEP(xb, yb, xa, ya, 1)
  STEP(xa, ya, xb, yb, 2)   STEP(xb, yb, xa, ya, 3)
  STEP(xa, ya, xb, yb, 4)   STEP(xb, yb, xa, ya, 5)
  STEP(xa, ya, xb, yb, 6)   STEP(xb, yb, xa, ya, 7)
  STEP(xa, ya, xb, yb, 8)   STEP(xb, yb, xa, ya, 9)
  STEP(xa, ya, xb, yb, 10)  STEP(xb, yb, xa, ya, 11)
  STEP(xa, ya, xb, yb, 12)  STEP(xb, yb, xa, ya, 13)
  STEP(xa, ya, xb, yb, 14)  STEP(xb, yb, xa, ya, 15)
  STEP(xa, ya, xb, yb, 16)  STEP(xb, yb, xa, ya, 17)
  STEP(xa, ya, xb, yb, 18)  STEP(xb, yb, xa, ya, 19)
#undef STEP

  // Block reduction. Counts packed pc|(tc<<16): per-block per-batch sums are
  // <= 4*BLK_F4 = 20480 < 65536, so no field overflow anywhere in the tree.
  __shared__ float sb[THREADS];
  __shared__ int   sA[THREADS];
  __shared__ int   sB[THREADS];
  sb[tid] = bce2;
  sA[tid] = pcA | (tcA << 16);
  sB[tid] = pcB | (tcB << 16);
  __syncthreads();
#pragma unroll
  for (int s = THREADS / 2; s > 0; s >>= 1) {
    if (tid < s) {
      sb[tid] += sb[tid + s];
      sA[tid] += sA[tid + s];
      sB[tid] += sB[tid + s];
    }
    __syncthreads();
  }
  if (tid == 0) {
    bce_part[blk] = sb[0] * (float)LN2;  // back to natural-log units
    comb_part[2 * blk]     = sA[0];
    comb_part[2 * blk + 1] = sB[0];
  }
}

// Kernel 2: single block. Double-precision BCE total; per-batch POR; compose.
__global__ __launch_bounds__(THREADS) void final_kernel(
    const float* __restrict__ bce_part, const int* __restrict__ comb_part,
    float* __restrict__ out) {
  const int tid = threadIdx.x;

  __shared__ double sred[THREADS];
  double local = 0.0;
  for (int i = tid; i < GRID_BLOCKS; i += THREADS) local += (double)bce_part[i];
  sred[tid] = local;
  __syncthreads();
#pragma unroll
  for (int s = THREADS / 2; s > 0; s >>= 1) {
    if (tid < s) sred[tid] += sred[tid + s];
    __syncthreads();
  }

  __shared__ int pcb[NBATCH], tcb[NBATCH];
  if (tid < NBATCH) { pcb[tid] = 0; tcb[tid] = 0; }
  __syncthreads();
  for (int i = tid; i < GRID_BLOCKS; i += THREADS) {
    const int s0 = (int)((unsigned)(i * BLK_F4) >> 19);
    const int cA = comb_part[2 * i];
    const int cB = comb_part[2 * i + 1];
    atomicAdd(&pcb[s0], cA & 0xFFFF);
    atomicAdd(&tcb[s0], (cA >> 16) & 0xFFFF);
    if (cB != 0 && s0 + 1 < NBATCH) {   // straddling block's second batch
      atomicAdd(&pcb[s0 + 1], cB & 0xFFFF);
      atomicAdd(&tcb[s0 + 1], (cB >> 16) & 0xFFFF);
    }
  }
  __syncthreads();

  __shared__ float spor[NBATCH];
  if (tid < NBATCH) {
    const float pp = (float)pcb[tid] / (float)ELEMS_PER_BATCH;
    const float pt = (float)tcb[tid] / (float)ELEMS_PER_BATCH;
    const float d = pp - pt;
    spor[tid] = d * d;
  }
  __syncthreads();

  if (tid == 0) {
    float pore_sum = 0.0f;
#pragma unroll
    for (int b = 0; b < NBATCH; ++b) pore_sum += spor[b];
    const float pore = pore_sum / (float)NBATCH;
    const double total = (double)NBATCH * (double)ELEMS_PER_BATCH;
    const float mse = (float)(-(sred[0] / total));
    out[0] = pore + mse;
    out[1] = pore;
  }
}

extern "C" void kernel_launch(void* const* d_in, const int* in_sizes, int n_in,
                              void* d_out, int out_size, void* d_ws, size_t ws_size,
                              hipStream_t stream) {
  const float* x = (const float*)d_in[0];
  const float* y = (const float*)d_in[1];
  float* out = (float*)d_out;

  // Workspace: [2048 floats bce][2048*2 ints packed counts] = 24 KB.
  // Every slot is fully overwritten by partial_kernel — no init needed.
  float* bce_part  = (float*)d_ws;
  int*   comb_part = (int*)(bce_part + GRID_BLOCKS);

  partial_kernel<<<GRID_BLOCKS, THREADS, 0, stream>>>(x, y, bce_part, comb_part);
  final_kernel<<<1, THREADS, 0, stream>>>(bce_part, comb_part, out);
}